// Round 13
// baseline (295.063 us; speedup 1.0000x reference)
//
#include <hip/hip_runtime.h>

// BasicRNN R12: k_step rebuilt m97-style. Diagnosis: direct-to-VGPR loads were
// MSHR/latency-bound (~22us vs 6.8us L1 floor, all pipes idle; waves/unroll didn't
// help). Fix: BK=128 double-buffered LDS staging via global_load_lds width=16
// (DMA path, no VGPR round-trip), ds_read_b128 fragments, 8 waves = 4 quadrants
// x 2-way K-split, one barrier per chunk. k_prep/k_out/launcher = R10 exact (best).
// Fragment-tiled operands:
//   elem(r,c) = frag*512 + lane*8 + (c&7), frag=(r>>5)*(C/16)+(c>>4), lane=(r&31)+32*((c>>3)&1)

typedef __bf16 bf16x8 __attribute__((ext_vector_type(8)));
typedef float  f32x16 __attribute__((ext_vector_type(16)));

#define TOTAL 4096
#define BATCH 256
#define INDIM 2048
#define SDIM  1024
#define NCLS  1000
#define KC    (TOTAL / 16)   // 256 k-chunks of 16

#define MFMA(a, b, c) __builtin_amdgcn_mfma_f32_32x32x16_bf16((a), (b), (c), 0, 0, 0)

__device__ inline f32x16 zero16() {
    f32x16 v;
#pragma unroll
    for (int i = 0; i < 16; ++i) v[i] = 0.f;
    return v;
}

__device__ inline void gload16(const __bf16* g, __bf16* l) {
    __builtin_amdgcn_global_load_lds(
        (const __attribute__((address_space(1))) void*)g,
        (__attribute__((address_space(3))) void*)l, 16, 0, 0);
}

__device__ inline void swz_slot(const float* __restrict__ in, __bf16* __restrict__ out,
                                int C, int Rvalid, int t) {
    const int lane = t & 63;
    const int frag = t >> 6;
    const int kcN = C >> 4;
    const int rt = frag / kcN;
    const int kc = frag - rt * kcN;
    const int r = rt * 32 + (lane & 31);
    const int c = kc * 16 + (lane >> 5) * 8;
    alignas(16) __bf16 v[8];
    if (r < Rvalid) {
        const float* p = in + (size_t)r * C + c;
#pragma unroll
        for (int j = 0; j < 8; ++j) v[j] = (__bf16)p[j];
    } else {
#pragma unroll
        for (int j = 0; j < 8; ++j) v[j] = (__bf16)0.f;
    }
    *(ulonglong2*)(out + (size_t)t * 8) = *(const ulonglong2*)v;
}

// ---- merged preprocessing + E-GEMM (R10 exact) ----
// grid 2816 x 256: [0,256) E-GEMM; [256,2304) W transpose-swizzle (16k x 512n tiles);
//                  [2304,2816) out_w swizzle
__global__ __launch_bounds__(256) void k_prep(const float* __restrict__ W,
                                              const float* __restrict__ x,
                                              const float* __restrict__ in_w,
                                              const float* __restrict__ in_b,
                                              const float* __restrict__ out_w,
                                              __bf16* __restrict__ WT,
                                              __bf16* __restrict__ OWT,
                                              float* __restrict__ Ebuf,
                                              __bf16* __restrict__ H0) {
    __shared__ float t[16 * 512];   // 32 KB; E path reuses first 4x1024 as reduce buf
    const int bid = blockIdx.x;
    const int tid = threadIdx.x;
    if (bid < 256) {
        float* red = t;   // 4 x 1024
        const int mt = bid >> 5, nt = bid & 31;
        const int wave = tid >> 6, lane = tid & 63;
        const int l31 = lane & 31, kh = (lane >> 5) * 8;
        const int k0 = wave * 512;
        const float* Ax = x    + (size_t)(mt * 32 + l31) * INDIM + k0 + kh;
        const float* Bw = in_w + (size_t)(nt * 32 + l31) * INDIM + k0 + kh;
        f32x16 acc = zero16();
#pragma unroll 4
        for (int i = 0; i < 32; ++i) {
            const float* pa = Ax + i * 16;
            const float* pb = Bw + i * 16;
            float4 a0 = *(const float4*)pa, a1 = *(const float4*)(pa + 4);
            float4 b0 = *(const float4*)pb, b1 = *(const float4*)(pb + 4);
            bf16x8 a, b;
            a[0] = (__bf16)a0.x; a[1] = (__bf16)a0.y; a[2] = (__bf16)a0.z; a[3] = (__bf16)a0.w;
            a[4] = (__bf16)a1.x; a[5] = (__bf16)a1.y; a[6] = (__bf16)a1.z; a[7] = (__bf16)a1.w;
            b[0] = (__bf16)b0.x; b[1] = (__bf16)b0.y; b[2] = (__bf16)b0.z; b[3] = (__bf16)b0.w;
            b[4] = (__bf16)b1.x; b[5] = (__bf16)b1.y; b[6] = (__bf16)b1.z; b[7] = (__bf16)b1.w;
            acc = MFMA(a, b, acc);
        }
#pragma unroll
        for (int r = 0; r < 16; ++r) {
            int row = (r & 3) + 8 * (r >> 2) + 4 * (lane >> 5);
            red[wave * 1024 + row * 32 + l31] = acc[r];
        }
        __syncthreads();
        const int e0 = tid * 4;
        float4 s = {0.f, 0.f, 0.f, 0.f};
#pragma unroll
        for (int w = 0; w < 4; ++w) {
            float4 v = *(const float4*)&red[w * 1024 + e0];
            s.x += v.x; s.y += v.y; s.z += v.z; s.w += v.w;
        }
        const int row = e0 >> 5, col = e0 & 31;
        const int m = mt * 32 + row, n = nt * 32 + col;
        float v[4] = {s.x + in_b[n], s.y + in_b[n + 1], s.z + in_b[n + 2], s.w + in_b[n + 3]};
        *(float4*)(Ebuf + m * SDIM + n) = *(const float4*)v;
        alignas(8) __bf16 o[4];
#pragma unroll
        for (int j = 0; j < 4; ++j) o[j] = (__bf16)fmaxf(v[j], 0.f);
        const size_t frag = (size_t)(m >> 5) * KC + (n >> 4);
        const int lh = (m & 31) + 32 * ((n >> 3) & 1);
        *(ushort4*)(H0 + frag * 512 + lh * 8 + (n & 7)) = *(const ushort4*)o;
    } else if (bid < 2304) {
        const int wb = bid - 256;
        const int k0 = (wb >> 3) * 16;
        const int n0 = (wb & 7) * 512;
#pragma unroll
        for (int i = 0; i < 8; ++i) {
            const int slot = i * 256 + tid;
            const int row = slot >> 7;
            const int c4 = (slot & 127) * 4;
            float4 v = *(const float4*)(W + (size_t)(k0 + row) * TOTAL + n0 + c4);
            *(float4*)&t[row * 512 + c4] = v;
        }
        __syncthreads();
        const int kcG = k0 >> 4;
#pragma unroll
        for (int s = tid; s < 1024; s += 256) {
            const int rtl = s >> 6;
            const int lane = s & 63;
            const int nl = rtl * 32 + (lane & 31);
            const int kl = (lane >> 5) * 8;
            bf16x8 v;
#pragma unroll
            for (int j = 0; j < 8; ++j) v[j] = (__bf16)t[(kl + j) * 512 + nl];
            const size_t fragG = (size_t)((n0 >> 5) + rtl) * KC + kcG;
            *(bf16x8*)(WT + fragG * 512 + lane * 8) = v;
        }
    } else {
        swz_slot(out_w, OWT, 1024, NCLS, (bid - 2304) * 256 + tid);
    }
}

// ---- one recurrence step: hn = relu(h @ W + gate*[E,0,0]) (h, hn, WT tiled) ----
// 256 blocks x 512 thr; tile 64m x 64n; K in BK=128 chunks, double-buffered LDS
// staging via global_load_lds; 8 waves = 4 quadrants x 2-way K-split.
// XCD-aware bid swizzle: all 4 mt of an nt-panel on one XCD (bid%8 ~ XCD id).
template <int NC, int GATE>   // NC = K/128 chunks
__global__ __launch_bounds__(512, 2) void k_step(const __bf16* __restrict__ h,
                                                 const __bf16* __restrict__ WT,
                                                 const float* __restrict__ E,
                                                 __bf16* __restrict__ hn) {
    __shared__ __align__(16) char smem[65536];
    __bf16* As = (__bf16*)smem;             // 2 bufs x 16 frags x 512 bf16 = 32 KB
    __bf16* Bs = (__bf16*)(smem + 32768);   // 32 KB
    const int wave = threadIdx.x >> 6;
    const int lane = threadIdx.x & 63;
    const int xcd = blockIdx.x & 7;
    const int idx = blockIdx.x >> 3;       // 0..31
    const int mt = idx & 3;                // m0 = mt*64
    const int nt = xcd * 8 + (idx >> 2);   // 0..63

    // staging sources: wave w stages kcl = w of each chunk, for A rtl 0/1 and B rtl 0/1
    const __bf16* pA0 = h  + ((size_t)(mt * 2) * KC + wave) * 512 + lane * 8;
    const __bf16* pA1 = pA0 + (size_t)KC * 512;
    const __bf16* pB0 = WT + ((size_t)(nt * 2) * KC + wave) * 512 + lane * 8;
    const __bf16* pB1 = pB0 + (size_t)KC * 512;
    // staging LDS destinations (wave-uniform base; HW scatters lane*16B)
    __bf16* dA0 = As + wave * 512;
    __bf16* dA1 = As + (8 + wave) * 512;
    __bf16* dB0 = Bs + wave * 512;
    __bf16* dB1 = Bs + (8 + wave) * 512;

    // compute assignment: quadrant q (mh,nh) and 2-way K-split ks
    const int q = wave & 3;
    const int ks = wave >> 2;
    const int mh = q >> 1, nh = q & 1;
    const int aoff = mh * 8 * 512 + lane * 8;
    const int boff = nh * 8 * 512 + lane * 8;

    f32x16 acc = zero16();

    // prologue: stage chunk 0 into buf 0
    gload16(pA0, dA0); gload16(pA1, dA1);
    gload16(pB0, dB0); gload16(pB1, dB1);
    __syncthreads();

    for (int c = 0; c < NC; ++c) {
        const int cur = (c & 1) * 8192;
        if (c + 1 < NC) {
            const size_t go = (size_t)(c + 1) * 4096;   // 8 frags x 512 elems
            const int nb = ((c + 1) & 1) * 8192;
            gload16(pA0 + go, dA0 + nb); gload16(pA1 + go, dA1 + nb);
            gload16(pB0 + go, dB0 + nb); gload16(pB1 + go, dB1 + nb);
        }
#pragma unroll
        for (int j = 0; j < 4; ++j) {
            const int kcl = ks * 4 + j;
            bf16x8 a = *(const bf16x8*)(As + cur + kcl * 512 + aoff);
            bf16x8 b = *(const bf16x8*)(Bs + cur + kcl * 512 + boff);
            acc = MFMA(a, b, acc);
        }
        __syncthreads();   // drains vmcnt (next chunk staged) + protects buffer reuse
    }

    // reduce ks=1 into ks=0 via LDS (reuse As region), then row-major to Bs region
    float* redD = (float*)smem;             // 16 KB
    float* redF = (float*)(smem + 32768);   // 16 KB
    if (ks == 1) {
#pragma unroll
        for (int r = 0; r < 16; ++r)
            redD[(q * 16 + r) * 64 + lane] = acc[r];
    }
    __syncthreads();
    if (ks == 0) {
        const int col = nh * 32 + (lane & 31);
#pragma unroll
        for (int r = 0; r < 16; ++r) {
            float s = acc[r] + redD[(q * 16 + r) * 64 + lane];
            const int row = mh * 32 + (r & 3) + 8 * (r >> 2) + 4 * (lane >> 5);
            redF[row * 64 + col] = s;
        }
    }
    __syncthreads();

    // epilogue: thread t -> (row, 8 cols from col0); redF is [64][64]
    const int t = threadIdx.x;
    const int row = t >> 3;
    const int col0 = (t & 7) * 8;
    float4 v0 = *(const float4*)&redF[row * 64 + col0];
    float4 v1 = *(const float4*)&redF[row * 64 + col0 + 4];
    float v[8] = {v0.x, v0.y, v0.z, v0.w, v1.x, v1.y, v1.z, v1.w};
    const int m = mt * 64 + row;
    const int n0g = nt * 64 + col0;
    if (GATE && n0g < SDIM) {
        const float* Ep = E + m * SDIM + n0g;
#pragma unroll
        for (int j = 0; j < 8; ++j) v[j] += Ep[j];
    }
    alignas(16) __bf16 o[8];
#pragma unroll
    for (int j = 0; j < 8; ++j) o[j] = (__bf16)fmaxf(v[j], 0.f);
    const size_t frag = (size_t)(m >> 5) * KC + (n0g >> 4);
    const int lh = (m & 31) + 32 * ((n0g >> 3) & 1);
    *(ulonglong2*)(hn + frag * 512 + lh * 8) = *(const ulonglong2*)o;
}

// ---- out = h[:, 3072:] @ out_w^T + out_b (h tiled, out_w tiled padded to 1024 rows) ----
__global__ __launch_bounds__(512, 4) void k_out(const __bf16* __restrict__ h,
                                                const __bf16* __restrict__ owt,
                                                const float* __restrict__ out_b,
                                                float* __restrict__ out) {
    __shared__ float red[8][1024];
    const int wave = threadIdx.x >> 6;
    const int lane = threadIdx.x & 63;
    const int mt = blockIdx.x >> 5;
    const int ct = blockIdx.x & 31;
    const int m0 = mt * 32, c0 = ct * 32;
    const int kcA0 = (3072 / 16) + wave * 8;
    const int kcB0 = wave * 8;
    const bf16x8* Ap = (const bf16x8*)h   + ((size_t)mt * KC + kcA0) * 64 + lane;
    const bf16x8* Bp = (const bf16x8*)owt + ((size_t)ct * (1024 / 16) + kcB0) * 64 + lane;
    f32x16 acc = zero16();
#pragma unroll
    for (int i = 0; i < 8; ++i)
        acc = MFMA(Ap[i * 64], Bp[i * 64], acc);
#pragma unroll
    for (int r = 0; r < 16; ++r) {
        int row = (r & 3) + 8 * (r >> 2) + 4 * (lane >> 5);
        red[wave][row * 32 + (lane & 31)] = acc[r];
    }
    __syncthreads();
    const int e0 = threadIdx.x * 2;
    float sx = 0.f, sy = 0.f;
#pragma unroll
    for (int w = 0; w < 8; ++w) {
        float2 v = *(const float2*)&red[w][e0];
        sx += v.x; sy += v.y;
    }
    const int row = e0 >> 5, col = e0 & 31;
    const int m = m0 + row;
    const int n = c0 + col;
    if (n < NCLS)     out[m * NCLS + n]     = sx + out_b[n];
    if (n + 1 < NCLS) out[m * NCLS + n + 1] = sy + out_b[n + 1];
}

extern "C" void kernel_launch(void* const* d_in, const int* in_sizes, int n_in,
                              void* d_out, int out_size, void* d_ws, size_t ws_size,
                              hipStream_t stream) {
    const float* x     = (const float*)d_in[0];   // 256 x 2048
    const float* W     = (const float*)d_in[1];   // 4096 x 4096
    const float* in_w  = (const float*)d_in[2];   // 1024 x 2048
    const float* in_b  = (const float*)d_in[3];   // 1024
    const float* out_w = (const float*)d_in[4];   // 1000 x 1024
    const float* out_b = (const float*)d_in[5];   // 1000
    float* out = (float*)d_out;                   // 256 x 1000

    char* ws = (char*)d_ws;
    __bf16* WT  = (__bf16*)(ws + 0);          // 32 MiB  W^T tiled (r=n, c=k)
    __bf16* OWT = (__bf16*)(ws + 33554432);   // 2 MiB   out_w tiled (padded 1024 rows)
    float*  Ebuf= (float*)(ws + 35651584);    // 1 MiB   E f32 row-major
    __bf16* H0  = (__bf16*)(ws + 36700160);   // 2 MiB   h tiled
    __bf16* H1  = (__bf16*)(ws + 38797312);   // 2 MiB   h tiled

    k_prep<<<2816, 256, 0, stream>>>(W, x, in_w, in_b, out_w, WT, OWT, Ebuf, H0);

    // t = 1..9 (gate fires at t=5); t=1 only needs K=1024 (8 chunks)
    const __bf16* hs = H0;
    __bf16* hd = H1;
    for (int t = 1; t < 10; ++t) {
        if (t == 1)
            k_step<8, 0><<<256, 512, 0, stream>>>(hs, WT, Ebuf, hd);
        else if (t == 5)
            k_step<32, 1><<<256, 512, 0, stream>>>(hs, WT, Ebuf, hd);
        else
            k_step<32, 0><<<256, 512, 0, stream>>>(hs, WT, Ebuf, hd);
        const __bf16* tmp = hs; hs = hd; hd = (__bf16*)tmp;
    }

    k_out<<<256, 512, 0, stream>>>(hs, OWT, out_b, out);
}

// Round 14
// 263.903 us; speedup vs baseline: 1.1181x; 1.1181x over previous
//
#include <hip/hip_runtime.h>

// BasicRNN R13: R10 exact (best, 263.6us) except k_prep W-phase tile widened to
// 16k x 1024n (64KB LDS stage): W rows read as 4KB contiguous (was 2KB) and W-block
// count halved -> half the concurrent DRAM page demand. k_step = R10 direct-load
// structure (5 alternative structures all regressed: R5/R8/R11/R12).
// Fragment-tiled operands:
//   elem(r,c) = frag*512 + lane*8 + (c&7), frag=(r>>5)*(C/16)+(c>>4), lane=(r&31)+32*((c>>3)&1)

typedef __bf16 bf16x8 __attribute__((ext_vector_type(8)));
typedef float  f32x16 __attribute__((ext_vector_type(16)));

#define TOTAL 4096
#define BATCH 256
#define INDIM 2048
#define SDIM  1024
#define NCLS  1000
#define KC    (TOTAL / 16)

#define MFMA(a, b, c) __builtin_amdgcn_mfma_f32_32x32x16_bf16((a), (b), (c), 0, 0, 0)

__device__ inline f32x16 zero16() {
    f32x16 v;
#pragma unroll
    for (int i = 0; i < 16; ++i) v[i] = 0.f;
    return v;
}

__device__ inline void swz_slot(const float* __restrict__ in, __bf16* __restrict__ out,
                                int C, int Rvalid, int t) {
    const int lane = t & 63;
    const int frag = t >> 6;
    const int kcN = C >> 4;
    const int rt = frag / kcN;
    const int kc = frag - rt * kcN;
    const int r = rt * 32 + (lane & 31);
    const int c = kc * 16 + (lane >> 5) * 8;
    alignas(16) __bf16 v[8];
    if (r < Rvalid) {
        const float* p = in + (size_t)r * C + c;
#pragma unroll
        for (int j = 0; j < 8; ++j) v[j] = (__bf16)p[j];
    } else {
#pragma unroll
        for (int j = 0; j < 8; ++j) v[j] = (__bf16)0.f;
    }
    *(ulonglong2*)(out + (size_t)t * 8) = *(const ulonglong2*)v;
}

// ---- merged preprocessing + E-GEMM ----
// grid 1792 x 256: [0,256) E-GEMM; [256,1280) W transpose-swizzle (16k x 1024n tiles);
//                  [1280,1792) out_w swizzle
__global__ __launch_bounds__(256) void k_prep(const float* __restrict__ W,
                                              const float* __restrict__ x,
                                              const float* __restrict__ in_w,
                                              const float* __restrict__ in_b,
                                              const float* __restrict__ out_w,
                                              __bf16* __restrict__ WT,
                                              __bf16* __restrict__ OWT,
                                              float* __restrict__ Ebuf,
                                              __bf16* __restrict__ H0) {
    __shared__ float t[16 * 1024];   // 64 KB; E path reuses first 4x1024 as reduce buf
    const int bid = blockIdx.x;
    const int tid = threadIdx.x;
    if (bid < 256) {
        // ---- E = x @ in_w^T + in_b ; H0[:, :1024] = relu(E) (tiled) ----
        float* red = t;   // 4 x 1024
        const int mt = bid >> 5, nt = bid & 31;
        const int wave = tid >> 6, lane = tid & 63;
        const int l31 = lane & 31, kh = (lane >> 5) * 8;
        const int k0 = wave * 512;
        const float* Ax = x    + (size_t)(mt * 32 + l31) * INDIM + k0 + kh;
        const float* Bw = in_w + (size_t)(nt * 32 + l31) * INDIM + k0 + kh;
        f32x16 acc = zero16();
#pragma unroll 4
        for (int i = 0; i < 32; ++i) {
            const float* pa = Ax + i * 16;
            const float* pb = Bw + i * 16;
            float4 a0 = *(const float4*)pa, a1 = *(const float4*)(pa + 4);
            float4 b0 = *(const float4*)pb, b1 = *(const float4*)(pb + 4);
            bf16x8 a, b;
            a[0] = (__bf16)a0.x; a[1] = (__bf16)a0.y; a[2] = (__bf16)a0.z; a[3] = (__bf16)a0.w;
            a[4] = (__bf16)a1.x; a[5] = (__bf16)a1.y; a[6] = (__bf16)a1.z; a[7] = (__bf16)a1.w;
            b[0] = (__bf16)b0.x; b[1] = (__bf16)b0.y; b[2] = (__bf16)b0.z; b[3] = (__bf16)b0.w;
            b[4] = (__bf16)b1.x; b[5] = (__bf16)b1.y; b[6] = (__bf16)b1.z; b[7] = (__bf16)b1.w;
            acc = MFMA(a, b, acc);
        }
#pragma unroll
        for (int r = 0; r < 16; ++r) {
            int row = (r & 3) + 8 * (r >> 2) + 4 * (lane >> 5);
            red[wave * 1024 + row * 32 + l31] = acc[r];
        }
        __syncthreads();
        const int e0 = tid * 4;
        float4 s = {0.f, 0.f, 0.f, 0.f};
#pragma unroll
        for (int w = 0; w < 4; ++w) {
            float4 v = *(const float4*)&red[w * 1024 + e0];
            s.x += v.x; s.y += v.y; s.z += v.z; s.w += v.w;
        }
        const int row = e0 >> 5, col = e0 & 31;
        const int m = mt * 32 + row, n = nt * 32 + col;
        float v[4] = {s.x + in_b[n], s.y + in_b[n + 1], s.z + in_b[n + 2], s.w + in_b[n + 3]};
        *(float4*)(Ebuf + m * SDIM + n) = *(const float4*)v;
        alignas(8) __bf16 o[4];
#pragma unroll
        for (int j = 0; j < 4; ++j) o[j] = (__bf16)fmaxf(v[j], 0.f);
        const size_t frag = (size_t)(m >> 5) * KC + (n >> 4);
        const int lh = (m & 31) + 32 * ((n >> 3) & 1);
        *(ushort4*)(H0 + frag * 512 + lh * 8 + (n & 7)) = *(const ushort4*)o;
    } else if (bid < 1280) {
        // ---- W (f32, W[k][n]) -> WT tiled bf16 (r=n, c=k); 16k x 1024n tile ----
        // reads: 4KB contiguous per row (4 float4/row-visit per thread group);
        // LDS t[k][n] written stride-1 float4 (conflict-free); emit = 8x ds_read_b32
        // column gather at bank = lane&31 (2-way alias = free).
        const int wb = bid - 256;
        const int k0 = (wb >> 2) * 16;      // 256 k-groups
        const int n0 = (wb & 3) * 1024;     // 4 n-panels
#pragma unroll
        for (int i = 0; i < 16; ++i) {
            const int slot = i * 256 + tid;        // 4096 float4 slots
            const int row = slot >> 8;             // 256 float4 per row
            const int c4 = (slot & 255) * 4;
            float4 v = *(const float4*)(W + (size_t)(k0 + row) * TOTAL + n0 + c4);
            *(float4*)&t[row * 1024 + c4] = v;
        }
        __syncthreads();
        const int kcG = k0 >> 4;
#pragma unroll
        for (int s = tid; s < 2048; s += 256) {
            const int rtl = s >> 6;          // 0..31
            const int lane = s & 63;
            const int nl = rtl * 32 + (lane & 31);
            const int kl = (lane >> 5) * 8;
            bf16x8 v;
#pragma unroll
            for (int j = 0; j < 8; ++j) v[j] = (__bf16)t[(kl + j) * 1024 + nl];
            const size_t fragG = (size_t)((n0 >> 5) + rtl) * KC + kcG;
            *(bf16x8*)(WT + fragG * 512 + lane * 8) = v;
        }
    } else {
        swz_slot(out_w, OWT, 1024, NCLS, (bid - 1280) * 256 + tid);
    }
}

// ---- one recurrence step: hn = relu(h @ W + gate*[E,0,0]) (h, hn, WT tiled) ----
// 256 blocks x 512 thr; block/wave tile 64m x 64n; 8 waves K-split (R10 exact).
// XCD-aware bid swizzle: all 4 mt of an nt-panel on one XCD (bid%8 ~ XCD id).
template <int CHUNKS>
__global__ __launch_bounds__(512, 2) void k_step(const __bf16* __restrict__ h,
                                                 const __bf16* __restrict__ WT,
                                                 const float* __restrict__ E,
                                                 const int gate,
                                                 __bf16* __restrict__ hn) {
    __shared__ float buf[4][4096];   // 64 KiB
    const int wave = threadIdx.x >> 6;
    const int lane = threadIdx.x & 63;
    const int xcd = blockIdx.x & 7;
    const int idx = blockIdx.x >> 3;       // 0..31
    const int mt = idx & 3;                // m0 = mt*64
    const int nt = xcd * 8 + (idx >> 2);   // 0..63
    constexpr int PER = CHUNKS >> 3;
    const int kc0 = wave * PER;

    const bf16x8* A0 = (const bf16x8*)h  + ((size_t)(mt * 2) * KC + kc0) * 64 + lane;
    const bf16x8* A1 = A0 + (size_t)KC * 64;
    const bf16x8* B0 = (const bf16x8*)WT + ((size_t)(nt * 2) * KC + kc0) * 64 + lane;
    const bf16x8* B1 = B0 + (size_t)KC * 64;

    f32x16 ac0 = zero16(), ac1 = zero16(), ac2 = zero16(), ac3 = zero16();
#pragma unroll 4
    for (int i = 0; i < PER; ++i) {
        const int off = i * 64;
        bf16x8 a0 = A0[off];
        bf16x8 a1 = A1[off];
        bf16x8 b0 = B0[off];
        bf16x8 b1 = B1[off];
        ac0 = MFMA(a0, b0, ac0);
        ac1 = MFMA(a0, b1, ac1);
        ac2 = MFMA(a1, b0, ac2);
        ac3 = MFMA(a1, b1, ac3);
    }

    // two-phase reduce: idx(c,r,l) = (c*16+r)*64 + l (2-way bank alias: free)
    f32x16 accs[4] = {ac0, ac1, ac2, ac3};
    if (wave >= 4) {
        float* b = buf[wave - 4];
#pragma unroll
        for (int c = 0; c < 4; ++c)
#pragma unroll
            for (int r = 0; r < 16; ++r)
                b[(c * 16 + r) * 64 + lane] = accs[c][r];
    }
    __syncthreads();
    if (wave < 4) {
        float* b = buf[wave];
#pragma unroll
        for (int c = 0; c < 4; ++c)
#pragma unroll
            for (int r = 0; r < 16; ++r) {
                const int i2 = (c * 16 + r) * 64 + lane;
                b[i2] += accs[c][r];
            }
    }
    __syncthreads();

    // final 4-way sum + epilogue; thread t -> (c, r, 8 lanes from l0)
    const int t = threadIdx.x;
    const int c = t >> 7;            // 0..3
    const int r = (t >> 3) & 15;     // 0..15
    const int l0 = (t & 7) * 8;      // 0..56
    const int base = (c * 16 + r) * 64 + l0;
    float4 s0 = {0.f, 0.f, 0.f, 0.f}, s1 = {0.f, 0.f, 0.f, 0.f};
#pragma unroll
    for (int w = 0; w < 4; ++w) {
        const float4* p = (const float4*)&buf[w][base];
        float4 v0 = p[0], v1 = p[1];
        s0.x += v0.x; s0.y += v0.y; s0.z += v0.z; s0.w += v0.w;
        s1.x += v1.x; s1.y += v1.y; s1.z += v1.z; s1.w += v1.w;
    }
    float v[8] = {s0.x, s0.y, s0.z, s0.w, s1.x, s1.y, s1.z, s1.w};
    const int ih = c >> 1, jh = c & 1;
    const int row = ih * 32 + (r & 3) + 8 * (r >> 2) + 4 * (l0 >> 5);
    const int col0 = jh * 32 + (l0 & 31);
    const int m = mt * 64 + row;
    const int n0g = nt * 64 + col0;
    if (gate && n0g < SDIM) {
        const float* Ep = E + m * SDIM + n0g;
#pragma unroll
        for (int j = 0; j < 8; ++j) v[j] += Ep[j];
    }
    alignas(16) __bf16 o[8];
#pragma unroll
    for (int j = 0; j < 8; ++j) o[j] = (__bf16)fmaxf(v[j], 0.f);
    const size_t frag = (size_t)(m >> 5) * KC + (n0g >> 4);
    const int lh = (m & 31) + 32 * ((n0g >> 3) & 1);
    *(ulonglong2*)(hn + frag * 512 + lh * 8) = *(const ulonglong2*)o;
}

// ---- out = h[:, 3072:] @ out_w^T + out_b (h tiled, out_w tiled padded to 1024 rows) ----
__global__ __launch_bounds__(512, 4) void k_out(const __bf16* __restrict__ h,
                                                const __bf16* __restrict__ owt,
                                                const float* __restrict__ out_b,
                                                float* __restrict__ out) {
    __shared__ float red[8][1024];
    const int wave = threadIdx.x >> 6;
    const int lane = threadIdx.x & 63;
    const int mt = blockIdx.x >> 5;
    const int ct = blockIdx.x & 31;
    const int m0 = mt * 32, c0 = ct * 32;
    const int kcA0 = (3072 / 16) + wave * 8;
    const int kcB0 = wave * 8;
    const bf16x8* Ap = (const bf16x8*)h   + ((size_t)mt * KC + kcA0) * 64 + lane;
    const bf16x8* Bp = (const bf16x8*)owt + ((size_t)ct * (1024 / 16) + kcB0) * 64 + lane;
    f32x16 acc = zero16();
#pragma unroll
    for (int i = 0; i < 8; ++i)
        acc = MFMA(Ap[i * 64], Bp[i * 64], acc);
#pragma unroll
    for (int r = 0; r < 16; ++r) {
        int row = (r & 3) + 8 * (r >> 2) + 4 * (lane >> 5);
        red[wave][row * 32 + (lane & 31)] = acc[r];
    }
    __syncthreads();
    const int e0 = threadIdx.x * 2;
    float sx = 0.f, sy = 0.f;
#pragma unroll
    for (int w = 0; w < 8; ++w) {
        float2 v = *(const float2*)&red[w][e0];
        sx += v.x; sy += v.y;
    }
    const int row = e0 >> 5, col = e0 & 31;
    const int m = m0 + row;
    const int n = c0 + col;
    if (n < NCLS)     out[m * NCLS + n]     = sx + out_b[n];
    if (n + 1 < NCLS) out[m * NCLS + n + 1] = sy + out_b[n + 1];
}

extern "C" void kernel_launch(void* const* d_in, const int* in_sizes, int n_in,
                              void* d_out, int out_size, void* d_ws, size_t ws_size,
                              hipStream_t stream) {
    const float* x     = (const float*)d_in[0];   // 256 x 2048
    const float* W     = (const float*)d_in[1];   // 4096 x 4096
    const float* in_w  = (const float*)d_in[2];   // 1024 x 2048
    const float* in_b  = (const float*)d_in[3];   // 1024
    const float* out_w = (const float*)d_in[4];   // 1000 x 1024
    const float* out_b = (const float*)d_in[5];   // 1000
    float* out = (float*)d_out;                   // 256 x 1000

    char* ws = (char*)d_ws;
    __bf16* WT  = (__bf16*)(ws + 0);          // 32 MiB  W^T tiled (r=n, c=k)
    __bf16* OWT = (__bf16*)(ws + 33554432);   // 2 MiB   out_w tiled (padded 1024 rows)
    float*  Ebuf= (float*)(ws + 35651584);    // 1 MiB   E f32 row-major
    __bf16* H0  = (__bf16*)(ws + 36700160);   // 2 MiB   h tiled
    __bf16* H1  = (__bf16*)(ws + 38797312);   // 2 MiB   h tiled

    k_prep<<<1792, 256, 0, stream>>>(W, x, in_w, in_b, out_w, WT, OWT, Ebuf, H0);

    // t = 1..9 (gate fires at t=5); t=1 only needs K=1024
    const __bf16* hs = H0;
    __bf16* hd = H1;
    for (int t = 1; t < 10; ++t) {
        const int gate = (t % 5 == 0) ? 1 : 0;
        if (t == 1)
            k_step<SDIM / 16><<<256, 512, 0, stream>>>(hs, WT, Ebuf, gate, hd);
        else
            k_step<TOTAL / 16><<<256, 512, 0, stream>>>(hs, WT, Ebuf, gate, hd);
        const __bf16* tmp = hs; hs = hd; hd = (__bf16*)tmp;
    }

    k_out<<<256, 512, 0, stream>>>(hs, OWT, out_b, out);
}